// Round 4
// baseline (258.313 us; speedup 1.0000x reference)
//
#include <hip/hip_runtime.h>
#include <stdint.h>

#define NEG_SLOPE 0.01f
#define HPG 32        // heads per block in k4_fused
#define TSTR 72       // padded T row stride (halfwords)
#define BSH 9         // head-bucket shift: bucket = head >> 9 (512 heads)
#define NBMAX 256     // max buckets (N=100K -> 196)
#define K1CH 4096     // edges per k1_bin block

typedef float f32x4 __attribute__((ext_vector_type(4)));
typedef short short8 __attribute__((ext_vector_type(8)));

// DPP-based butterfly adds (VALU, ~4cy vs ~120cy ds_swizzle):
// 0xB1 = quad_perm [1,0,3,2] (xor1), 0x4E = quad_perm [2,3,0,1] (xor2),
// 0x141 = row_half_mirror (xor-within-8 after quads are uniform),
// 0x128 = row_ror:8 (swap 8-halves within the 16-lane row).
#define DPPADD(v, ctrl) ((v) + __int_as_float(__builtin_amdgcn_update_dpp( \
        0, __float_as_int(v), (ctrl), 0xF, 0xF, true)))

__device__ inline short f2bf(float f) {
    union { float f; uint32_t u; } x; x.f = f;
    uint32_t r = x.u + 0x7FFF + ((x.u >> 16) & 1);   // RNE
    return (short)(r >> 16);
}
__device__ inline float bf2f(unsigned short u) {
    union { uint32_t u; float f; } x; x.u = ((uint32_t)u) << 16; return x.f;
}

// ---- K_init: zero head counters + ego fp32->bf16 + W^T frag pack ----------
__global__ void __launch_bounds__(256) k_init_bf(
        const float* __restrict__ ego, unsigned short* __restrict__ ego_bf,
        int NE8, int* head_cnt, int N,
        const float* __restrict__ rw, short* __restrict__ wfrag) {
    int i = blockIdx.x * 256 + threadIdx.x;
    if (i < N) head_cnt[i] = 0;
    if (blockIdx.x < 16) {                 // W^T frag pack: blocks 0..15
        int r = blockIdx.x;
        int tid = threadIdx.x;
        int lane = tid & 63;
        int c = lane & 15, q = lane >> 4;
        for (int ph = 0; ph < 2; ++ph) {
            int pair = (tid >> 6) + ph * 4;
            int t4 = pair >> 1, kh = pair & 1;
            int m = t4 * 16 + c;
            short8 f;
            for (int j = 0; j < 8; ++j) {
                int k = kh * 32 + q * 8 + j;
                f[j] = f2bf(rw[r * 4096 + k * 64 + m]);
            }
            *(short8*)(wfrag + ((size_t)((r * 4 + t4) * 2 + kh) * 64 + lane) * 8) = f;
        }
    }
    if (i >= NE8) return;
    const float4* p = (const float4*)ego + (size_t)i * 2;
    float4 a = p[0], b = p[1];
    short8 v;
    v[0] = f2bf(a.x); v[1] = f2bf(a.y); v[2] = f2bf(a.z); v[3] = f2bf(a.w);
    v[4] = f2bf(b.x); v[5] = f2bf(b.y); v[6] = f2bf(b.z); v[7] = f2bf(b.w);
    *(short8*)(ego_bf + (size_t)i * 8) = v;
}

// ---- K1: count (fire-and-forget atomic) + block-major bucket binning ------
// staging[blk*K1CH + loff[bk] + rank] = {h, tail|type<<20}; per-block bucket
// offsets go to blk_off[blk][0..NB] so k3b can walk each bucket's segments.
__global__ void __launch_bounds__(512) k1_bin(
        const int* __restrict__ head, const int* __restrict__ tail,
        const int* __restrict__ etype, int E, int NB,
        int* head_cnt, int2* __restrict__ staging, int* __restrict__ blk_off) {
    __shared__ int lcnt[NBMAX], loff[NBMAX];
    int t = threadIdx.x;
    for (int b = t; b < NBMAX; b += 512) lcnt[b] = 0;
    __syncthreads();
    long long base = (long long)blockIdx.x * K1CH;
    int myh[8], myrk[8], myp[8];
    #pragma unroll
    for (int s = 0; s < 8; ++s) {
        long long e = base + t + s * 512;
        int h = -1, rk = 0, p = 0;
        if (e < E) {
            h = head[e];
            p = tail[e] | (etype[e] << 20);
            rk = atomicAdd(&lcnt[h >> BSH], 1);
            atomicAdd(&head_cnt[h], 1);          // result unused -> no-return
        }
        myh[s] = h; myrk[s] = rk; myp[s] = p;
    }
    __syncthreads();
    if (t < 64) {                          // exclusive scan of lcnt, one wave
        int c0 = lcnt[t * 4], c1 = lcnt[t * 4 + 1];
        int c2 = lcnt[t * 4 + 2], c3 = lcnt[t * 4 + 3];
        int cs = c0 + c1 + c2 + c3;
        int inc = cs;
        for (int off = 1; off < 64; off <<= 1) {
            int u = __shfl_up(inc, off);
            if (t >= off) inc += u;
        }
        int run = inc - cs;
        loff[t * 4] = run; run += c0;
        loff[t * 4 + 1] = run; run += c1;
        loff[t * 4 + 2] = run; run += c2;
        loff[t * 4 + 3] = run;
    }
    __syncthreads();
    int* bo = blk_off + (size_t)blockIdx.x * (NBMAX + 1);
    for (int b = t; b < NB; b += 512) bo[b] = loff[b];
    if (t == 0) {
        long long nv = (long long)E - base;
        bo[NB] = (int)(nv < K1CH ? nv : K1CH);
    }
    #pragma unroll
    for (int s = 0; s < 8; ++s) {
        if (myh[s] >= 0) {
            int bk = myh[s] >> BSH;
            int2 rec; rec.x = myh[s]; rec.y = myp[s];
            staging[base + loff[bk] + myrk[s]] = rec;   // own 32KB window
        }
    }
}

// ---- K2a: per-block partial sums of head_cnt -------------------------------
__global__ void __launch_bounds__(512) k2a(const int* __restrict__ head_cnt,
                                           int N, int* partial) {
    __shared__ int sw[8];
    int i = blockIdx.x * 512 + threadIdx.x;
    int v = (i < N) ? head_cnt[i] : 0;
    for (int off = 32; off; off >>= 1) v += __shfl_down(v, off);
    int w = threadIdx.x >> 6, lane = threadIdx.x & 63;
    if (lane == 0) sw[w] = v;
    __syncthreads();
    if (threadIdx.x == 0) {
        int s = 0;
        for (int j = 0; j < 8; ++j) s += sw[j];
        partial[blockIdx.x] = s;
    }
}

// ---- K2c: scan -> head_off -------------------------------------------------
__global__ void __launch_bounds__(512) k2c(const int* __restrict__ head_cnt,
                                           int N, const int* __restrict__ partial,
                                           int* head_off, int E) {
    __shared__ int s[512];
    __shared__ int bo_s;
    int t = threadIdx.x;
    if (t < 64) {
        int acc = 0;
        for (int i = t; i < blockIdx.x; i += 64) acc += partial[i];
        for (int off = 32; off; off >>= 1) acc += __shfl_down(acc, off);
        if (t == 0) bo_s = acc;
    }
    int i = blockIdx.x * 512 + t;
    int v = (i < N) ? head_cnt[i] : 0;
    s[t] = v;
    __syncthreads();
    for (int off = 1; off < 512; off <<= 1) {
        int x = (t >= off) ? s[t - off] : 0;
        __syncthreads();
        s[t] += x;
        __syncthreads();
    }
    if (i < N) head_off[i] = s[t] - v + bo_s;
    if (i == 0) head_off[N] = E;
}

// ---- K3b: per-bucket rank via LDS atomics + window-local placement ---------
// One block per 512-head bucket; wave w walks k1-blocks w, w+8, ... Each
// bucket's recs2 destination range (~26KB) is written by exactly this block.
__global__ void __launch_bounds__(512) k3b_rank(
        const int2* __restrict__ staging, const int* __restrict__ blk_off,
        int nblk, int NB, const int* __restrict__ head_off,
        int* __restrict__ recs2) {
    __shared__ int lcnt[1 << BSH];
    int t = threadIdx.x;
    lcnt[t] = 0;
    __syncthreads();
    int b = blockIdx.x;
    int hbase = b << BSH;
    int wv = t >> 6, ln = t & 63;
    for (int blk = wv; blk < nblk; blk += 8) {
        const int* bo = blk_off + (size_t)blk * (NBMAX + 1) + b;
        int o0 = bo[0], o1 = bo[1];
        for (int i = o0 + ln; i < o1; i += 64) {
            int2 rec = staging[(size_t)blk * K1CH + i];
            int rk = atomicAdd(&lcnt[rec.x - hbase], 1);
            recs2[head_off[rec.x] + rk] = rec.y;
        }
    }
}

// ---- K4: fused transform + score + softmax + aggregate ---------------------
__global__ void __launch_bounds__(512, 4) k4_fused(
        const unsigned short* __restrict__ ego_bf,
        const short* __restrict__ wfrag,
        const int* __restrict__ recs2,
        const int* __restrict__ head_off,
        float* __restrict__ out, int N) {
    __shared__ unsigned short T[16 * HPG * TSTR];   // 73,728 B -> 2 blocks/CU
    int tid = threadIdx.x;
    int wave = tid >> 6;
    int lane = tid & 63;
    int c = lane & 15, q = lane >> 4;
    int hb = blockIdx.x * HPG;

    // ---------------- phase 1: per-wave 2 types x 32 heads ----------------
    for (int t = 0; t < 2; ++t) {
        int r = wave * 2 + t;
        const short* wp = wfrag + (size_t)r * 4096;
        short8 wf[4][2];
        #pragma unroll
        for (int t4 = 0; t4 < 4; ++t4)
            #pragma unroll
            for (int kh = 0; kh < 2; ++kh)
                wf[t4][kh] = *(const short8*)(wp + ((size_t)((t4 * 2 + kh) * 64 + lane)) * 8);
        #pragma unroll
        for (int hf = 0; hf < 2; ++hf) {
            int hrow = hb + hf * 16 + c;
            if (hrow >= N) hrow = N - 1;           // clamp; garbage T never read
            const unsigned short* hr = ego_bf + (size_t)hrow * 64;
            short8 b0 = *(const short8*)(hr + q * 8);
            short8 b1 = *(const short8*)(hr + 32 + q * 8);
            #pragma unroll
            for (int t4 = 0; t4 < 4; ++t4) {
                f32x4 a = {0.f, 0.f, 0.f, 0.f};
                a = __builtin_amdgcn_mfma_f32_16x16x32_bf16(wf[t4][0], b0, a, 0, 0, 0);
                a = __builtin_amdgcn_mfma_f32_16x16x32_bf16(wf[t4][1], b1, a, 0, 0, 0);
                ushort4 us;
                us.x = (unsigned short)f2bf(a[0]);
                us.y = (unsigned short)f2bf(a[1]);
                us.z = (unsigned short)f2bf(a[2]);
                us.w = (unsigned short)f2bf(a[3]);
                *(ushort4*)&T[(size_t)(r * HPG + hf * 16 + c) * TSTR + t4 * 16 + q * 4] = us;
            }
        }
    }
    __syncthreads();

    // ---------------- phase 2: quarter (wave,q) owns head hb + wave*4 + q --
    int hql = wave * 4 + q;
    int h = hb + hql;
    if (h >= N) return;
    int lq = c;                   // lane within quarter
    int g2 = lq >> 3, c8 = lq & 7;
    int s0 = head_off[h], s1 = head_off[h + 1];
    int cnt = s1 - s0;
    float acc[8] = {0.f, 0.f, 0.f, 0.f, 0.f, 0.f, 0.f, 0.f};
    float den = 0.f;
    for (int base = s0; base < s1; base += 16) {
        int ng = s1 - base; if (ng > 16) ng = 16;
        int rj[8];
        #pragma unroll
        for (int sIt = 0; sIt < 8; ++sIt) {        // 8-lane group: same addr ->
            int idx = base + sIt * 2 + g2;         // HW broadcast, no bpermute
            rj[sIt] = (idx < s1) ? recs2[idx] : 0;
        }
        short8 rows[8];
        #pragma unroll
        for (int sIt = 0; sIt < 8; ++sIt)          // all 8 gathers in flight
            if (sIt * 2 < ng)
                rows[sIt] = *(const short8*)(ego_bf + (size_t)(rj[sIt] & 0xFFFFF) * 64 + c8 * 8);
        short8 trw[8];
        #pragma unroll
        for (int sIt = 0; sIt < 8; ++sIt)          // all 8 T-reads in flight
            if (sIt * 2 < ng)
                trw[sIt] = *(const short8*)&T[(size_t)((rj[sIt] >> 20) * HPG + hql) * TSTR + c8 * 8];
        #pragma unroll
        for (int sIt = 0; sIt < 8; ++sIt) {
            if (sIt * 2 < ng) {
                float rf[8];
                float sa = 0.f, sb = 0.f;          // two chains halve fmac dep
                #pragma unroll
                for (int k = 0; k < 4; ++k) {
                    rf[k] = bf2f((unsigned short)rows[sIt][k]);
                    sa += rf[k] * bf2f((unsigned short)trw[sIt][k]);
                }
                #pragma unroll
                for (int k = 4; k < 8; ++k) {
                    rf[k] = bf2f((unsigned short)rows[sIt][k]);
                    sb += rf[k] * bf2f((unsigned short)trw[sIt][k]);
                }
                float s = sa + sb;
                s = DPPADD(s, 0xB1);               // xor1 (quad_perm)
                s = DPPADD(s, 0x4E);               // xor2 (quad_perm)
                s = DPPADD(s, 0x141);              // other quad (half mirror)
                float lr = s > 0.f ? s : NEG_SLOPE * s;
                float w = (sIt * 2 + g2 < ng) ? __expf(lr) : 0.f;
                den += w;
                #pragma unroll
                for (int k = 0; k < 8; ++k) acc[k] += w * rf[k];
            }
        }
    }
    den = DPPADD(den, 0x128);                      // combine 2 edge slots
    #pragma unroll
    for (int k = 0; k < 8; ++k) acc[k] = DPPADD(acc[k], 0x128);
    if (g2 == 0) {
        float sc = (cnt > 0) ? 1.f / (den * (float)cnt) : 0.f;
        float4 v0 = {acc[0] * sc, acc[1] * sc, acc[2] * sc, acc[3] * sc};
        float4 v1 = {acc[4] * sc, acc[5] * sc, acc[6] * sc, acc[7] * sc};
        float* op = out + (size_t)h * 64 + c8 * 8;
        *(float4*)op = v0;
        *(float4*)(op + 4) = v1;
    }
}

extern "C" void kernel_launch(void* const* d_in, const int* in_sizes, int n_in,
                              void* d_out, int out_size, void* d_ws, size_t ws_size,
                              hipStream_t stream) {
    const float* ego = (const float*)d_in[0];
    const float* rw  = (const float*)d_in[1];
    const int* eidx  = (const int*)d_in[2];
    const int* etyp  = (const int*)d_in[3];
    int N = in_sizes[0] / 64;
    int E = in_sizes[3];
    const int* head = eidx;
    const int* tail = eidx + E;
    float* out = (float*)d_out;

    char* ws = (char*)d_ws;
    size_t o = 0;
    auto take = [&](size_t bytes) -> char* {
        char* p = ws + o;
        o = (o + bytes + 255) & ~(size_t)255;
        return p;
    };
    int nb2 = (N + 511) / 512;
    int NB = (N + (1 << BSH) - 1) >> BSH;
    if (NB > NBMAX) NB = NBMAX;            // defensive; N=100K -> 196
    int nblk = (E + K1CH - 1) / K1CH;
    unsigned short* ego_bf = (unsigned short*)take((size_t)N * 64 * 2);
    short* wfrag    = (short*)take(16 * 4096 * 2);
    int* recs2      = (int*)take((size_t)E * 4);
    int2* staging   = (int2*)take((size_t)nblk * K1CH * 8);
    int* blk_off    = (int*)take((size_t)nblk * (NBMAX + 1) * 4);
    int* head_cnt   = (int*)take((size_t)N * 4);
    int* head_off   = (int*)take((size_t)(N + 1) * 4);
    int* partial    = (int*)take((size_t)nb2 * 4);
    (void)ws_size; (void)n_in; (void)out_size;

    int NE8 = N * 8;
    k_init_bf<<<(NE8 + 255) / 256, 256, 0, stream>>>(ego, ego_bf, NE8,
                                                     head_cnt, N, rw, wfrag);
    k1_bin<<<nblk, 512, 0, stream>>>(head, tail, etyp, E, NB,
                                     head_cnt, staging, blk_off);
    k2a<<<nb2, 512, 0, stream>>>(head_cnt, N, partial);
    k2c<<<nb2, 512, 0, stream>>>(head_cnt, N, partial, head_off, E);
    k3b_rank<<<NB, 512, 0, stream>>>(staging, blk_off, nblk, NB, head_off, recs2);
    k4_fused<<<(N + HPG - 1) / HPG, 512, 0, stream>>>(ego_bf, wfrag, recs2,
                                                      head_off, out, N);
}

// Round 5
// 239.712 us; speedup vs baseline: 1.0776x; 1.0776x over previous
//
#include <hip/hip_runtime.h>
#include <stdint.h>

#define NEG_SLOPE 0.01f
#define HPG 32        // heads per block in k4_fused
#define TSTR 72       // padded T row stride (halfwords)
#define BSH 8         // head-bucket shift: bucket = head >> 8 (256 heads)
#define NBMAX 512     // max buckets (N=100K -> 391)
#define K1CH 8192     // edges per k1_bin block

typedef float f32x4 __attribute__((ext_vector_type(4)));
typedef short short8 __attribute__((ext_vector_type(8)));

// DPP butterfly adds (VALU): 0xB1 quad_perm xor1, 0x4E quad_perm xor2,
// 0x141 row_half_mirror (combines the two quads of an 8-group),
// 0x128 row_ror:8 (xor-8 within the 16-lane row).
#define DPPADD(v, ctrl) ((v) + __int_as_float(__builtin_amdgcn_update_dpp( \
        0, __float_as_int(v), (ctrl), 0xF, 0xF, true)))

__device__ inline short f2bf(float f) {
    union { float f; uint32_t u; } x; x.f = f;
    uint32_t r = x.u + 0x7FFF + ((x.u >> 16) & 1);   // RNE
    return (short)(r >> 16);
}
__device__ inline float bf2f(unsigned short u) {
    union { uint32_t u; float f; } x; x.u = ((uint32_t)u) << 16; return x.f;
}

// ---- K_init: zero head counters + ego fp32->bf16 + W^T frag pack ----------
__global__ void __launch_bounds__(256) k_init_bf(
        const float* __restrict__ ego, unsigned short* __restrict__ ego_bf,
        int NE8, int* head_cnt, int N,
        const float* __restrict__ rw, short* __restrict__ wfrag) {
    int i = blockIdx.x * 256 + threadIdx.x;
    if (i < N) head_cnt[i] = 0;
    if (blockIdx.x < 16) {                 // W^T frag pack: blocks 0..15
        int r = blockIdx.x;
        int tid = threadIdx.x;
        int lane = tid & 63;
        int c = lane & 15, q = lane >> 4;
        for (int ph = 0; ph < 2; ++ph) {
            int pair = (tid >> 6) + ph * 4;
            int t4 = pair >> 1, kh = pair & 1;
            int m = t4 * 16 + c;
            short8 f;
            for (int j = 0; j < 8; ++j) {
                int k = kh * 32 + q * 8 + j;
                f[j] = f2bf(rw[r * 4096 + k * 64 + m]);
            }
            *(short8*)(wfrag + ((size_t)((r * 4 + t4) * 2 + kh) * 64 + lane) * 8) = f;
        }
    }
    if (i >= NE8) return;
    const float4* p = (const float4*)ego + (size_t)i * 2;
    float4 a = p[0], b = p[1];
    short8 v;
    v[0] = f2bf(a.x); v[1] = f2bf(a.y); v[2] = f2bf(a.z); v[3] = f2bf(a.w);
    v[4] = f2bf(b.x); v[5] = f2bf(b.y); v[6] = f2bf(b.z); v[7] = f2bf(b.w);
    *(short8*)(ego_bf + (size_t)i * 8) = v;
}

// ---- K1: count (fire-and-forget atomic) + block-major bucket binning ------
__global__ void __launch_bounds__(512, 2) k1_bin(
        const int* __restrict__ head, const int* __restrict__ tail,
        const int* __restrict__ etype, int E, int NB,
        int* head_cnt, int2* __restrict__ staging, int* __restrict__ blk_off) {
    __shared__ int lcnt[NBMAX], loff[NBMAX];
    int t = threadIdx.x;
    for (int b = t; b < NBMAX; b += 512) lcnt[b] = 0;
    __syncthreads();
    long long base = (long long)blockIdx.x * K1CH;
    int myh[16], myrk[16], myp[16];
    #pragma unroll
    for (int s = 0; s < 16; ++s) {
        long long e = base + t + s * 512;
        int h = -1, rk = 0, p = 0;
        if (e < E) {
            h = head[e];
            p = tail[e] | (etype[e] << 20);
            rk = atomicAdd(&lcnt[h >> BSH], 1);
            atomicAdd(&head_cnt[h], 1);          // result unused -> no-return
        }
        myh[s] = h; myrk[s] = rk; myp[s] = p;
    }
    __syncthreads();
    if (t < 64) {                          // exclusive scan, 8 buckets/lane
        int cl[8]; int cs = 0;
        #pragma unroll
        for (int j = 0; j < 8; ++j) { cl[j] = lcnt[t * 8 + j]; cs += cl[j]; }
        int inc = cs;
        for (int off = 1; off < 64; off <<= 1) {
            int u = __shfl_up(inc, off);
            if (t >= off) inc += u;
        }
        int run = inc - cs;
        #pragma unroll
        for (int j = 0; j < 8; ++j) { loff[t * 8 + j] = run; run += cl[j]; }
    }
    __syncthreads();
    int* bo = blk_off + (size_t)blockIdx.x * (NBMAX + 1);
    for (int b = t; b < NB; b += 512) bo[b] = loff[b];
    if (t == 0) {
        long long nv = (long long)E - base;
        bo[NB] = (int)(nv < K1CH ? nv : K1CH);
    }
    #pragma unroll
    for (int s = 0; s < 16; ++s) {
        if (myh[s] >= 0) {
            int bk = myh[s] >> BSH;
            int2 rec; rec.x = myh[s]; rec.y = myp[s];
            staging[base + loff[bk] + myrk[s]] = rec;   // own 64KB window
        }
    }
}

// ---- K2a: per-block partial sums of head_cnt -------------------------------
__global__ void __launch_bounds__(512) k2a(const int* __restrict__ head_cnt,
                                           int N, int* partial) {
    __shared__ int sw[8];
    int i = blockIdx.x * 512 + threadIdx.x;
    int v = (i < N) ? head_cnt[i] : 0;
    for (int off = 32; off; off >>= 1) v += __shfl_down(v, off);
    int w = threadIdx.x >> 6, lane = threadIdx.x & 63;
    if (lane == 0) sw[w] = v;
    __syncthreads();
    if (threadIdx.x == 0) {
        int s = 0;
        for (int j = 0; j < 8; ++j) s += sw[j];
        partial[blockIdx.x] = s;
    }
}

// ---- K2c: scan -> head_off -------------------------------------------------
__global__ void __launch_bounds__(512) k2c(const int* __restrict__ head_cnt,
                                           int N, const int* __restrict__ partial,
                                           int* head_off, int E) {
    __shared__ int s[512];
    __shared__ int bo_s;
    int t = threadIdx.x;
    if (t < 64) {
        int acc = 0;
        for (int i = t; i < blockIdx.x; i += 64) acc += partial[i];
        for (int off = 32; off; off >>= 1) acc += __shfl_down(acc, off);
        if (t == 0) bo_s = acc;
    }
    int i = blockIdx.x * 512 + t;
    int v = (i < N) ? head_cnt[i] : 0;
    s[t] = v;
    __syncthreads();
    for (int off = 1; off < 512; off <<= 1) {
        int x = (t >= off) ? s[t - off] : 0;
        __syncthreads();
        s[t] += x;
        __syncthreads();
    }
    if (i < N) head_off[i] = s[t] - v + bo_s;
    if (i == 0) head_off[N] = E;
}

// ---- K3b: per-bucket rank via LDS atomics + window-local placement ---------
// One block per 256-head bucket (391 blocks -> full machine); wave w walks
// k1-blocks w, w+8, ... Dest range per bucket ~13KB, L2-local.
__global__ void __launch_bounds__(512) k3b_rank(
        const int2* __restrict__ staging, const int* __restrict__ blk_off,
        int nblk, int NB, const int* __restrict__ head_off,
        int* __restrict__ recs2) {
    __shared__ int lcnt[1 << BSH];
    int t = threadIdx.x;
    if (t < (1 << BSH)) lcnt[t] = 0;
    __syncthreads();
    int b = blockIdx.x;
    int hbase = b << BSH;
    int wv = t >> 6, ln = t & 63;
    for (int blk = wv; blk < nblk; blk += 8) {
        const int* bo = blk_off + (size_t)blk * (NBMAX + 1) + b;
        int o0 = bo[0], o1 = bo[1];
        for (int i = o0 + ln; i < o1; i += 64) {
            int2 rec = staging[(size_t)blk * K1CH + i];
            int rk = atomicAdd(&lcnt[rec.x - hbase], 1);
            recs2[head_off[rec.x] + rk] = rec.y;
        }
    }
}

// ---- K4: fused transform + score + softmax + aggregate ---------------------
// Phase 2 is 2-deep software-pipelined: load recL[b+2] / extract+gather b+1 /
// compute b — the random tail gathers get a full compute section in flight.
__global__ void __launch_bounds__(512, 4) k4_fused(
        const unsigned short* __restrict__ ego_bf,
        const short* __restrict__ wfrag,
        const int* __restrict__ recs2,
        const int* __restrict__ head_off,
        float* __restrict__ out, int N) {
    __shared__ unsigned short T[16 * HPG * TSTR];   // 73,728 B -> 2 blocks/CU
    int tid = threadIdx.x;
    int wave = tid >> 6;
    int lane = tid & 63;
    int c = lane & 15, q = lane >> 4;
    int hb = blockIdx.x * HPG;

    // ---------------- phase 1: per-wave 2 types x 32 heads ----------------
    for (int t = 0; t < 2; ++t) {
        int r = wave * 2 + t;
        const short* wp = wfrag + (size_t)r * 4096;
        short8 wf[4][2];
        #pragma unroll
        for (int t4 = 0; t4 < 4; ++t4)
            #pragma unroll
            for (int kh = 0; kh < 2; ++kh)
                wf[t4][kh] = *(const short8*)(wp + ((size_t)((t4 * 2 + kh) * 64 + lane)) * 8);
        #pragma unroll
        for (int hf = 0; hf < 2; ++hf) {
            int hrow = hb + hf * 16 + c;
            if (hrow >= N) hrow = N - 1;           // clamp; garbage T never read
            const unsigned short* hr = ego_bf + (size_t)hrow * 64;
            short8 b0 = *(const short8*)(hr + q * 8);
            short8 b1 = *(const short8*)(hr + 32 + q * 8);
            #pragma unroll
            for (int t4 = 0; t4 < 4; ++t4) {
                f32x4 a = {0.f, 0.f, 0.f, 0.f};
                a = __builtin_amdgcn_mfma_f32_16x16x32_bf16(wf[t4][0], b0, a, 0, 0, 0);
                a = __builtin_amdgcn_mfma_f32_16x16x32_bf16(wf[t4][1], b1, a, 0, 0, 0);
                ushort4 us;
                us.x = (unsigned short)f2bf(a[0]);
                us.y = (unsigned short)f2bf(a[1]);
                us.z = (unsigned short)f2bf(a[2]);
                us.w = (unsigned short)f2bf(a[3]);
                *(ushort4*)&T[(size_t)(r * HPG + hf * 16 + c) * TSTR + t4 * 16 + q * 4] = us;
            }
        }
    }
    __syncthreads();

    // ---------------- phase 2: quarter (wave,q) owns head hb + wave*4 + q --
    int hql = wave * 4 + q;
    int h = hb + hql;
    if (h >= N) return;
    int lq = c;                   // lane within quarter
    int g2 = lq >> 3, c8 = lq & 7;
    int qb = q * 16;
    int s0 = head_off[h], s1 = head_off[h + 1];
    int cnt = s1 - s0;
    int nb = (cnt + 15) >> 4;
    float acc[8] = {0.f, 0.f, 0.f, 0.f, 0.f, 0.f, 0.f, 0.f};
    float den = 0.f;

    auto loadRec = [&](int b) -> int {             // one coalesced 4B/lane load
        if (b >= nb) return 0;
        int idx = s0 + b * 16 + lq;
        return (idx < s1) ? recs2[idx] : 0;
    };

    int rjA[8]; short8 rowsA[8];
    int recL1;
    {
        int recL0 = loadRec(0);
        #pragma unroll
        for (int j = 0; j < 8; ++j) rjA[j] = __shfl(recL0, qb + j * 2 + g2);
        #pragma unroll
        for (int j = 0; j < 8; ++j)
            rowsA[j] = *(const short8*)(ego_bf + (size_t)(rjA[j] & 0xFFFFF) * 64 + c8 * 8);
        recL1 = loadRec(1);
    }
    for (int b = 0; b < nb; ++b) {
        int recL2 = loadRec(b + 2);                // S(b+2)
        int rjB[8]; short8 rowsB[8];
        #pragma unroll
        for (int j = 0; j < 8; ++j) rjB[j] = __shfl(recL1, qb + j * 2 + g2);
        #pragma unroll
        for (int j = 0; j < 8; ++j)                // G(b+1): in flight across C(b)
            rowsB[j] = *(const short8*)(ego_bf + (size_t)(rjB[j] & 0xFFFFF) * 64 + c8 * 8);
        int ng = s1 - (s0 + b * 16); if (ng > 16) ng = 16;
        #pragma unroll
        for (int sIt = 0; sIt < 8; ++sIt) {        // C(b)
            if (sIt * 2 < ng) {
                short8 trw = *(const short8*)&T[(size_t)((rjA[sIt] >> 20) * HPG + hql) * TSTR + c8 * 8];
                float rf[8];
                float sa = 0.f, sb = 0.f;
                #pragma unroll
                for (int k = 0; k < 4; ++k) {
                    rf[k] = bf2f((unsigned short)rowsA[sIt][k]);
                    sa += rf[k] * bf2f((unsigned short)trw[k]);
                }
                #pragma unroll
                for (int k = 4; k < 8; ++k) {
                    rf[k] = bf2f((unsigned short)rowsA[sIt][k]);
                    sb += rf[k] * bf2f((unsigned short)trw[k]);
                }
                float s = sa + sb;
                s = DPPADD(s, 0xB1);               // xor1
                s = DPPADD(s, 0x4E);               // xor2
                s = DPPADD(s, 0x141);              // other quad
                float lr = s > 0.f ? s : NEG_SLOPE * s;
                float w = (sIt * 2 + g2 < ng) ? __expf(lr) : 0.f;
                den += w;
                #pragma unroll
                for (int k = 0; k < 8; ++k) acc[k] += w * rf[k];
            }
        }
        recL1 = recL2;
        #pragma unroll
        for (int j = 0; j < 8; ++j) { rjA[j] = rjB[j]; rowsA[j] = rowsB[j]; }
    }
    den = DPPADD(den, 0x128);                      // combine 2 edge slots
    #pragma unroll
    for (int k = 0; k < 8; ++k) acc[k] = DPPADD(acc[k], 0x128);
    if (g2 == 0) {
        float sc = (cnt > 0) ? 1.f / (den * (float)cnt) : 0.f;
        float4 v0 = {acc[0] * sc, acc[1] * sc, acc[2] * sc, acc[3] * sc};
        float4 v1 = {acc[4] * sc, acc[5] * sc, acc[6] * sc, acc[7] * sc};
        float* op = out + (size_t)h * 64 + c8 * 8;
        *(float4*)op = v0;
        *(float4*)(op + 4) = v1;
    }
}

extern "C" void kernel_launch(void* const* d_in, const int* in_sizes, int n_in,
                              void* d_out, int out_size, void* d_ws, size_t ws_size,
                              hipStream_t stream) {
    const float* ego = (const float*)d_in[0];
    const float* rw  = (const float*)d_in[1];
    const int* eidx  = (const int*)d_in[2];
    const int* etyp  = (const int*)d_in[3];
    int N = in_sizes[0] / 64;
    int E = in_sizes[3];
    const int* head = eidx;
    const int* tail = eidx + E;
    float* out = (float*)d_out;

    char* ws = (char*)d_ws;
    size_t o = 0;
    auto take = [&](size_t bytes) -> char* {
        char* p = ws + o;
        o = (o + bytes + 255) & ~(size_t)255;
        return p;
    };
    int nb2 = (N + 511) / 512;
    int NB = (N + (1 << BSH) - 1) >> BSH;
    if (NB > NBMAX) NB = NBMAX;            // defensive; N=100K -> 391
    int nblk = (E + K1CH - 1) / K1CH;
    unsigned short* ego_bf = (unsigned short*)take((size_t)N * 64 * 2);
    short* wfrag    = (short*)take(16 * 4096 * 2);
    int* recs2      = (int*)take((size_t)E * 4);
    int2* staging   = (int2*)take((size_t)nblk * K1CH * 8);
    int* blk_off    = (int*)take((size_t)nblk * (NBMAX + 1) * 4);
    int* head_cnt   = (int*)take((size_t)N * 4);
    int* head_off   = (int*)take((size_t)(N + 1) * 4);
    int* partial    = (int*)take((size_t)nb2 * 4);
    (void)ws_size; (void)n_in; (void)out_size;

    int NE8 = N * 8;
    k_init_bf<<<(NE8 + 255) / 256, 256, 0, stream>>>(ego, ego_bf, NE8,
                                                     head_cnt, N, rw, wfrag);
    k1_bin<<<nblk, 512, 0, stream>>>(head, tail, etyp, E, NB,
                                     head_cnt, staging, blk_off);
    k2a<<<nb2, 512, 0, stream>>>(head_cnt, N, partial);
    k2c<<<nb2, 512, 0, stream>>>(head_cnt, N, partial, head_off, E);
    k3b_rank<<<NB, 512, 0, stream>>>(staging, blk_off, nblk, NB, head_off, recs2);
    k4_fused<<<(N + HPG - 1) / HPG, 512, 0, stream>>>(ego_bf, wfrag, recs2,
                                                      head_off, out, N);
}